// Round 9
// baseline (95.471 us; speedup 1.0000x reference)
//
#include <hip/hip_runtime.h>

#define BB 8
#define TT 256
#define UU 64
#define VV 512
#define U1 (UU + 1)
#define GSTRIDE 66              // Dg groups per batch (64 live + 2 prefetch pad)
#define ZSTRIDE 264             // z64 entries per batch (256 live + 8 pad)

#define LOG2E 1.4426950408889634f
#define LN2   0.6931471805599453f
#define NEG_INF (-__builtin_inff())

typedef float floatx4 __attribute__((ext_vector_type(4)));

__device__ __forceinline__ float rdlane63(float x) {
    return __int_as_float(__builtin_amdgcn_readlane(__float_as_int(x), 63));
}

template<int CTRL, int RMASK>
__device__ __forceinline__ float dpp_mov(float v, float oldv) {
    int r = __builtin_amdgcn_update_dpp(__float_as_int(oldv), __float_as_int(v),
                                        CTRL, RMASK, 0xf, false);
    return __int_as_float(r);
}

// wave64 inclusive add-scan via DPP (identity = 0); strictly low-lane -> high-lane.
__device__ __forceinline__ float wave_addscan(float v) {
    v += dpp_mov<0x111, 0xf>(v, 0.f);
    v += dpp_mov<0x112, 0xf>(v, 0.f);
    v += dpp_mov<0x114, 0xf>(v, 0.f);
    v += dpp_mov<0x118, 0xf>(v, 0.f);
    v += dpp_mov<0x142, 0xa>(v, 0.f);
    v += dpp_mov<0x143, 0xc>(v, 0.f);
    return v;
}
// wave64 inclusive max-scan (identity = -inf); lane 63 = global max.
__device__ __forceinline__ float wave_maxscan(float v) {
    v = fmaxf(v, dpp_mov<0x111, 0xf>(v, NEG_INF));
    v = fmaxf(v, dpp_mov<0x112, 0xf>(v, NEG_INF));
    v = fmaxf(v, dpp_mov<0x114, 0xf>(v, NEG_INF));
    v = fmaxf(v, dpp_mov<0x118, 0xf>(v, NEG_INF));
    v = fmaxf(v, dpp_mov<0x142, 0xa>(v, NEG_INF));
    v = fmaxf(v, dpp_mov<0x143, 0xc>(v, NEG_INF));
    return v;
}

// One alpha-recursion step. (m,s) pairs; exps hoisted off the fs chain; 1 exp/logadd.
__device__ __forceinline__ void scan_step(float r, float z, float& am, float& as,
                                          float& a64m, float& a64s) {
    // max chain (critical path): 6 x (dpp + fmax)
    float f0 = am + r;
    float p1 = dpp_mov<0x111, 0xf>(f0, NEG_INF); float m1 = fmaxf(f0, p1);
    float p2 = dpp_mov<0x112, 0xf>(m1, NEG_INF); float m2 = fmaxf(m1, p2);
    float p3 = dpp_mov<0x114, 0xf>(m2, NEG_INF); float m3 = fmaxf(m2, p3);
    float p4 = dpp_mov<0x118, 0xf>(m3, NEG_INF); float m4 = fmaxf(m3, p4);
    float p5 = dpp_mov<0x142, 0xa>(m4, NEG_INF); float m5 = fmaxf(m4, p5);
    float p6 = dpp_mov<0x143, 0xc>(m5, NEG_INF); float m6 = fmaxf(m5, p6);
    // all exps derive from the max chain only -> pipelined, off the fs chain
    float e1 = exp2f(-fabsf(f0 - p1));
    float e2 = exp2f(-fabsf(m1 - p2));
    float e3 = exp2f(-fabsf(m2 - p3));
    float e4 = exp2f(-fabsf(m3 - p4));
    float e5 = exp2f(-fabsf(m4 - p5));
    float e6 = exp2f(-fabsf(m5 - p6));
    bool c1 = f0 >= p1, c2 = m1 >= p2, c3 = m2 >= p3,
         c4 = m3 >= p4, c5 = m4 >= p5, c6 = m5 >= p6;
    // fs chain: 6 x (dpp + 2 cndmask + fma), no trans ops
    float s_ = as;
    { float ps = dpp_mov<0x111, 0xf>(s_, 0.f); float bg = c1 ? s_ : ps, sm = c1 ? ps : s_; s_ = fmaf(sm, e1, bg); }
    { float ps = dpp_mov<0x112, 0xf>(s_, 0.f); float bg = c2 ? s_ : ps, sm = c2 ? ps : s_; s_ = fmaf(sm, e2, bg); }
    { float ps = dpp_mov<0x114, 0xf>(s_, 0.f); float bg = c3 ? s_ : ps, sm = c3 ? ps : s_; s_ = fmaf(sm, e3, bg); }
    { float ps = dpp_mov<0x118, 0xf>(s_, 0.f); float bg = c4 ? s_ : ps, sm = c4 ? ps : s_; s_ = fmaf(sm, e4, bg); }
    { float ps = dpp_mov<0x142, 0xa>(s_, 0.f); float bg = c5 ? s_ : ps, sm = c5 ? ps : s_; s_ = fmaf(sm, e5, bg); }
    { float ps = dpp_mov<0x143, 0xc>(s_, 0.f); float bg = c6 ? s_ : ps, sm = c6 ? ps : s_; s_ = fmaf(sm, e6, bg); }
    // u=64 side-chain (valid at lane 63), 1 exp
    float f64 = a64m + z;
    bool  cc  = f64 >= m6;
    float ee  = exp2f(-fabsf(f64 - m6));
    float bg = cc ? a64s : s_, sm = cc ? s_ : a64s;
    a64s = fmaf(sm, ee, bg);
    a64m = cc ? f64 : m6;
    am = m6; as = s_;
}

// Kernel 1: per-row log-softmax; extract blank lp and target (emit) lp.
// CULLED: rows with t >= loglen[b] or u > tgtlen[b] are dead.
__global__ __launch_bounds__(256) void k_logsm(const float* __restrict__ logits,
                                               const int* __restrict__ targets,
                                               const int* __restrict__ loglen,
                                               const int* __restrict__ tgtlen,
                                               float* __restrict__ blank,
                                               float* __restrict__ emit) {
    int wave = (int)((blockIdx.x * blockDim.x + threadIdx.x) >> 6);
    int lane = threadIdx.x & 63;
    const int nrows = BB * TT * U1;
    if (wave >= nrows) return;
    int u  = wave % U1;
    int bt = wave / U1;
    int b  = bt / TT;
    int t  = bt - b * TT;
    if (t >= loglen[b] || u > tgtlen[b]) return;   // dead row

    const float* row = logits + (size_t)wave * VV;
    floatx4 v0 = *(const floatx4*)(row + lane * 4);
    floatx4 v1 = *(const floatx4*)(row + 256 + lane * 4);
    float m8 = fmaxf(fmaxf(fmaxf(v0.x, v0.y), fmaxf(v0.z, v0.w)),
                     fmaxf(fmaxf(v1.x, v1.y), fmaxf(v1.z, v1.w)));
    float M = rdlane63(wave_maxscan(m8));          // uniform global max, VALU-only
    float s8 = __expf(v0.x - M) + __expf(v0.y - M) + __expf(v0.z - M) + __expf(v0.w - M)
             + __expf(v1.x - M) + __expf(v1.y - M) + __expf(v1.z - M) + __expf(v1.w - M);
    float S = rdlane63(wave_addscan(s8));
    float lse = M + __logf(S);

    if (lane == 0) blank[wave] = v0.x - lse;
    if (u < UU) {
        int tgt = targets[b * UU + u];             // in [1, V)
        int owner = (tgt & 255) >> 2;
        if (lane == owner) {
            int slot = tgt & 3;
            float x0 = (tgt < 256) ? v0.x : v1.x;
            float x1 = (tgt < 256) ? v0.y : v1.y;
            float x2 = (tgt < 256) ? v0.z : v1.z;
            float x3 = (tgt < 256) ? v0.w : v1.w;
            float val = (slot == 0) ? x0 : (slot == 1) ? x1 : (slot == 2) ? x2 : x3;
            emit[bt * UU + u] = val - lse;
        }
    }
}

// Kernel 2: build cum (exclusive, nat log) and D/z64 (log2 domain) for the scan.
__global__ __launch_bounds__(256) void k_prep(const float* __restrict__ emit,
                                              const float* __restrict__ blank,
                                              const int* __restrict__ loglen,
                                              float* __restrict__ cum,
                                              float* __restrict__ Dg,
                                              float* __restrict__ z64,
                                              float* __restrict__ out0) {
    int wave = (int)((blockIdx.x * blockDim.x + threadIdx.x) >> 6);
    int l = threadIdx.x & 63;
    if (wave >= BB * TT) return;
    if (wave == 0 && l == 0) out0[0] = 0.f;   // zero output for k_scan's atomicAdd
    int b = wave >> 8, t = wave & 255;
    if (t >= loglen[b]) return;               // scan's live region never reads past t_sel
    float e = emit[wave * UU + l];
    float incl = wave_addscan(e);
    float excl = incl - e;                    // exact 0 at lane 0
    cum[wave * U1 + l] = excl;
    float inclT63 = rdlane63(incl);
    if (l == 63) cum[wave * U1 + 64] = incl;
    if (t >= 1) {
        float eP = emit[(wave - 1) * UU + l];
        float inclP = wave_addscan(eP);
        float exclP = inclP - eP;
        float bl = blank[(size_t)(wave - 1) * U1 + l];
        int s = t - 1;
        Dg[((b * GSTRIDE + (s >> 2)) * 64 + l) * 4 + (s & 3)] = (bl + exclP - excl) * LOG2E;
        float inclP63 = rdlane63(inclP);
        if (l == 0)
            z64[b * ZSTRIDE + s] = (blank[(size_t)(wave - 1) * U1 + 64] + inclP63 - inclT63) * LOG2E;
    }
}

// Kernel 3: per-batch alpha recursion; (m,s) pairs. ALL loads unconditional
// (padded buffers) so the compiler can use counted vmcnt instead of vmcnt(0)
// drains; all 256 steps always run (post-t_sel steps are harmless finite garbage;
// gm/gs latched at s==t_sel).
__global__ __launch_bounds__(64) void k_scan(const float* __restrict__ Dg,
                                             const float* __restrict__ z64,
                                             const float* __restrict__ cum,
                                             const float* __restrict__ blank,
                                             const int* __restrict__ loglen,
                                             const int* __restrict__ tgtlen,
                                             float* __restrict__ out) {
    int b = blockIdx.x;
    int l = threadIdx.x;                  // owns u = l (0..63); u=64 side-chain in lane 63
    int t_idx = loglen[b] - 1;
    int u_idx = tgtlen[b];
    int t_sel = t_idx - 1;
    const float* Db = Dg + (size_t)b * GSTRIDE * 64 * 4;
    const float* zb = z64 + (size_t)b * ZSTRIDE;

    bool rec_main = (l == u_idx);
    bool rec_side = (u_idx == 64) && (l == 63);

    float am = 0.f, as = 1.f;             // g pair, g = am + log2(as)
    float a64m = 0.f, a64s = 1.f;
    float gm = 0.f, gs = 1.f;

    float rA[4], zA[4], rB[4], zB[4], rC[4], zC[4];

#define LOADG(r_, z_, c_) do { int c__ = (c_);                                   \
        *(float4*)(r_) = *(const float4*)(Db + (c__ * 64 + l) * 4);              \
        *(float4*)(z_) = *(const float4*)(zb + 4 * c__);                         \
    } while (0)

#define STEP4(r_, z_, c_) do { int cbase = 4 * (c_);                             \
        _Pragma("unroll")                                                        \
        for (int i = 0; i < 4; ++i) {                                            \
            int s = cbase + i;                                                   \
            scan_step(r_[i], z_[i], am, as, a64m, a64s);                         \
            bool hit = (s == t_sel);                                             \
            gm = (hit && rec_main) ? am   : gm;                                  \
            gs = (hit && rec_main) ? as   : gs;                                  \
            gm = (hit && rec_side) ? a64m : gm;                                  \
            gs = (hit && rec_side) ? a64s : gs;                                  \
        }                                                                        \
        { int e1; as = frexpf(as, &e1); am += (float)e1;                         \
          int e2; a64s = frexpf(a64s, &e2); a64m += (float)e2; }                 \
    } while (0)

    LOADG(rA, zA, 0);
    LOADG(rB, zB, 1);
    LOADG(rC, zC, 2);

    for (int cc = 0; cc < 21; ++cc) {
        STEP4(rA, zA, 3 * cc + 0);  LOADG(rA, zA, 3 * cc + 3);
        STEP4(rB, zB, 3 * cc + 1);  LOADG(rB, zB, 3 * cc + 4);
        STEP4(rC, zC, 3 * cc + 2);  LOADG(rC, zC, 3 * cc + 5);
    }
    STEP4(rA, zA, 63);

    int writer_lane = (u_idx < 64) ? u_idx : 63;
    if (l == writer_lane) {
        float g = (gm + log2f(gs)) * LN2;
        size_t idx = ((size_t)b * 256 + t_idx) * U1 + u_idx;
        float a  = cum[idx] + g;
        float fb = blank[idx];
        atomicAdd(out, -0.125f * (a + fb));
    }
#undef LOADG
#undef STEP4
}

extern "C" void kernel_launch(void* const* d_in, const int* in_sizes, int n_in,
                              void* d_out, int out_size, void* d_ws, size_t ws_size,
                              hipStream_t stream) {
    const float* logits  = (const float*)d_in[0];
    const int*   targets = (const int*)d_in[1];
    const int*   loglen  = (const int*)d_in[2];
    const int*   tgtlen  = (const int*)d_in[3];

    float* ws    = (float*)d_ws;
    float* blank = ws;                           // B*T*(U+1) = 133120
    float* emit  = blank + BB * TT * U1;         // B*T*U     = 131072
    float* cum   = emit  + BB * TT * UU;         // B*T*(U+1) = 133120
    float* Dg    = cum   + BB * TT * U1;         // 8*66*64*4 = 135168 (padded)
    float* z64   = Dg    + BB * GSTRIDE * 64 * 4; // 8*264    = 2112  (padded)

    const int nrows = BB * TT * U1;
    k_logsm<<<nrows / 4, 256, 0, stream>>>(logits, targets, loglen, tgtlen, blank, emit);
    k_prep<<<(BB * TT) / 4, 256, 0, stream>>>(emit, blank, loglen, cum, Dg, z64, (float*)d_out);
    k_scan<<<BB, 64, 0, stream>>>(Dg, z64, cum, blank, loglen, tgtlen, (float*)d_out);
}

// Round 10
// 86.149 us; speedup vs baseline: 1.1082x; 1.1082x over previous
//
#include <hip/hip_runtime.h>

#define BB 8
#define TT 256
#define UU 64
#define VV 512
#define U1 (UU + 1)
#define GSTRIDE 66              // Dg groups per batch (64 live + 2 prefetch pad)
#define ZSTRIDE 264             // z64 entries per batch (256 live + 8 pad)

#define LOG2E 1.4426950408889634f
#define LN2   0.6931471805599453f
#define NEG_INF (-__builtin_inff())

typedef float floatx4 __attribute__((ext_vector_type(4)));

// native base-2 transcendentals (single HW instruction, no libcall)
__device__ __forceinline__ float vexp2(float x) {
    float r; asm("v_exp_f32 %0, %1" : "=v"(r) : "v"(x)); return r;
}
__device__ __forceinline__ float vlog2(float x) {
    float r; asm("v_log_f32 %0, %1" : "=v"(r) : "v"(x)); return r;
}
// -|x| via sign-bit set (1 v_or_b32)
__device__ __forceinline__ float negabs(float x) {
    return __int_as_float(__float_as_int(x) | 0x80000000u);
}
__device__ __forceinline__ float rdlane63(float x) {
    return __int_as_float(__builtin_amdgcn_readlane(__float_as_int(x), 63));
}

template<int CTRL, int RMASK>
__device__ __forceinline__ float dpp_mov(float v, float oldv) {
    int r = __builtin_amdgcn_update_dpp(__float_as_int(oldv), __float_as_int(v),
                                        CTRL, RMASK, 0xf, false);
    return __int_as_float(r);
}

// wave64 inclusive add-scan via DPP (identity = 0); strictly low-lane -> high-lane.
__device__ __forceinline__ float wave_addscan(float v) {
    v += dpp_mov<0x111, 0xf>(v, 0.f);
    v += dpp_mov<0x112, 0xf>(v, 0.f);
    v += dpp_mov<0x114, 0xf>(v, 0.f);
    v += dpp_mov<0x118, 0xf>(v, 0.f);
    v += dpp_mov<0x142, 0xa>(v, 0.f);
    v += dpp_mov<0x143, 0xc>(v, 0.f);
    return v;
}
// wave64 inclusive max-scan (identity = -inf); lane 63 = global max.
__device__ __forceinline__ float wave_maxscan(float v) {
    v = fmaxf(v, dpp_mov<0x111, 0xf>(v, NEG_INF));
    v = fmaxf(v, dpp_mov<0x112, 0xf>(v, NEG_INF));
    v = fmaxf(v, dpp_mov<0x114, 0xf>(v, NEG_INF));
    v = fmaxf(v, dpp_mov<0x118, 0xf>(v, NEG_INF));
    v = fmaxf(v, dpp_mov<0x142, 0xa>(v, NEG_INF));
    v = fmaxf(v, dpp_mov<0x143, 0xc>(v, NEG_INF));
    return v;
}

// One alpha-recursion step. (m,s) pairs; exps hoisted off the fs chain; 1 exp/logadd.
__device__ __forceinline__ void scan_step(float r, float z, float& am, float& as,
                                          float& a64m, float& a64s) {
    // max chain (critical path): 6 x (dpp + fmax)
    float f0 = am + r;
    float p1 = dpp_mov<0x111, 0xf>(f0, NEG_INF); float m1 = fmaxf(f0, p1);
    float p2 = dpp_mov<0x112, 0xf>(m1, NEG_INF); float m2 = fmaxf(m1, p2);
    float p3 = dpp_mov<0x114, 0xf>(m2, NEG_INF); float m3 = fmaxf(m2, p3);
    float p4 = dpp_mov<0x118, 0xf>(m3, NEG_INF); float m4 = fmaxf(m3, p4);
    float p5 = dpp_mov<0x142, 0xa>(m4, NEG_INF); float m5 = fmaxf(m4, p5);
    float p6 = dpp_mov<0x143, 0xc>(m5, NEG_INF); float m6 = fmaxf(m5, p6);
    // all exps derive from the max chain only -> pipelined, off the fs chain
    float e1 = vexp2(negabs(f0 - p1));
    float e2 = vexp2(negabs(m1 - p2));
    float e3 = vexp2(negabs(m2 - p3));
    float e4 = vexp2(negabs(m3 - p4));
    float e5 = vexp2(negabs(m4 - p5));
    float e6 = vexp2(negabs(m5 - p6));
    bool c1 = f0 >= p1, c2 = m1 >= p2, c3 = m2 >= p3,
         c4 = m3 >= p4, c5 = m4 >= p5, c6 = m5 >= p6;
    // fs chain: 6 x (dpp + 2 cndmask + fma), no trans ops
    float s_ = as;
    { float ps = dpp_mov<0x111, 0xf>(s_, 0.f); float bg = c1 ? s_ : ps, sm = c1 ? ps : s_; s_ = fmaf(sm, e1, bg); }
    { float ps = dpp_mov<0x112, 0xf>(s_, 0.f); float bg = c2 ? s_ : ps, sm = c2 ? ps : s_; s_ = fmaf(sm, e2, bg); }
    { float ps = dpp_mov<0x114, 0xf>(s_, 0.f); float bg = c3 ? s_ : ps, sm = c3 ? ps : s_; s_ = fmaf(sm, e3, bg); }
    { float ps = dpp_mov<0x118, 0xf>(s_, 0.f); float bg = c4 ? s_ : ps, sm = c4 ? ps : s_; s_ = fmaf(sm, e4, bg); }
    { float ps = dpp_mov<0x142, 0xa>(s_, 0.f); float bg = c5 ? s_ : ps, sm = c5 ? ps : s_; s_ = fmaf(sm, e5, bg); }
    { float ps = dpp_mov<0x143, 0xc>(s_, 0.f); float bg = c6 ? s_ : ps, sm = c6 ? ps : s_; s_ = fmaf(sm, e6, bg); }
    // u=64 side-chain (valid at lane 63), 1 exp
    float f64 = a64m + z;
    bool  cc  = f64 >= m6;
    float ee  = vexp2(negabs(f64 - m6));
    float bg = cc ? a64s : s_, sm = cc ? s_ : a64s;
    a64s = fmaf(sm, ee, bg);
    a64m = cc ? f64 : m6;
    am = m6; as = s_;
}

// Kernel 1: per-row log-softmax; extract blank lp and target (emit) lp.
// CULLED: rows with t >= loglen[b] or u > tgtlen[b] are dead.
__global__ __launch_bounds__(256) void k_logsm(const float* __restrict__ logits,
                                               const int* __restrict__ targets,
                                               const int* __restrict__ loglen,
                                               const int* __restrict__ tgtlen,
                                               float* __restrict__ blank,
                                               float* __restrict__ emit) {
    int wave = (int)((blockIdx.x * blockDim.x + threadIdx.x) >> 6);
    int lane = threadIdx.x & 63;
    const int nrows = BB * TT * U1;
    if (wave >= nrows) return;
    int u  = wave % U1;
    int bt = wave / U1;
    int b  = bt / TT;
    int t  = bt - b * TT;
    if (t >= loglen[b] || u > tgtlen[b]) return;   // dead row

    const float* row = logits + (size_t)wave * VV;
    floatx4 v0 = __builtin_nontemporal_load((const floatx4*)(row + lane * 4));
    floatx4 v1 = __builtin_nontemporal_load((const floatx4*)(row + 256 + lane * 4));
    float m8 = fmaxf(fmaxf(fmaxf(v0.x, v0.y), fmaxf(v0.z, v0.w)),
                     fmaxf(fmaxf(v1.x, v1.y), fmaxf(v1.z, v1.w)));
    float M = rdlane63(wave_maxscan(m8));          // uniform global max, VALU-only
    float s8 = __expf(v0.x - M) + __expf(v0.y - M) + __expf(v0.z - M) + __expf(v0.w - M)
             + __expf(v1.x - M) + __expf(v1.y - M) + __expf(v1.z - M) + __expf(v1.w - M);
    float S = rdlane63(wave_addscan(s8));
    float lse = M + __logf(S);

    if (lane == 0) blank[wave] = v0.x - lse;
    if (u < UU) {
        int tgt = targets[b * UU + u];             // in [1, V)
        int owner = (tgt & 255) >> 2;
        if (lane == owner) {
            int slot = tgt & 3;
            float x0 = (tgt < 256) ? v0.x : v1.x;
            float x1 = (tgt < 256) ? v0.y : v1.y;
            float x2 = (tgt < 256) ? v0.z : v1.z;
            float x3 = (tgt < 256) ? v0.w : v1.w;
            float val = (slot == 0) ? x0 : (slot == 1) ? x1 : (slot == 2) ? x2 : x3;
            emit[bt * UU + u] = val - lse;
        }
    }
}

// Kernel 2: build cum (exclusive, nat log) and D/z64 (log2 domain) for the scan.
__global__ __launch_bounds__(256) void k_prep(const float* __restrict__ emit,
                                              const float* __restrict__ blank,
                                              const int* __restrict__ loglen,
                                              float* __restrict__ cum,
                                              float* __restrict__ Dg,
                                              float* __restrict__ z64,
                                              float* __restrict__ out0) {
    int wave = (int)((blockIdx.x * blockDim.x + threadIdx.x) >> 6);
    int l = threadIdx.x & 63;
    if (wave >= BB * TT) return;
    if (wave == 0 && l == 0) out0[0] = 0.f;   // zero output for k_scan's atomicAdd
    int b = wave >> 8, t = wave & 255;
    if (t >= loglen[b]) return;               // scan's live region never reads past t_sel
    float e = emit[wave * UU + l];
    float incl = wave_addscan(e);
    float excl = incl - e;                    // exact 0 at lane 0
    cum[wave * U1 + l] = excl;
    float inclT63 = rdlane63(incl);
    if (l == 63) cum[wave * U1 + 64] = incl;
    if (t >= 1) {
        float eP = emit[(wave - 1) * UU + l];
        float inclP = wave_addscan(eP);
        float exclP = inclP - eP;
        float bl = blank[(size_t)(wave - 1) * U1 + l];
        int s = t - 1;
        Dg[((b * GSTRIDE + (s >> 2)) * 64 + l) * 4 + (s & 3)] = (bl + exclP - excl) * LOG2E;
        float inclP63 = rdlane63(inclP);
        if (l == 0)
            z64[b * ZSTRIDE + s] = (blank[(size_t)(wave - 1) * U1 + 64] + inclP63 - inclT63) * LOG2E;
    }
}

// Kernel 3: per-batch alpha recursion; (m,s) pairs. ALL loads unconditional
// (padded buffers), all 256 steps always run (branch-free body -> compiler can
// count vmcnt instead of draining); gm/gs latched branchlessly at s==t_sel.
__global__ __launch_bounds__(64) void k_scan(const float* __restrict__ Dg,
                                             const float* __restrict__ z64,
                                             const float* __restrict__ cum,
                                             const float* __restrict__ blank,
                                             const int* __restrict__ loglen,
                                             const int* __restrict__ tgtlen,
                                             float* __restrict__ out) {
    int b = blockIdx.x;
    int l = threadIdx.x;                  // owns u = l (0..63); u=64 side-chain in lane 63
    int t_idx = loglen[b] - 1;
    int u_idx = tgtlen[b];
    int t_sel = t_idx - 1;
    const float* Db = Dg + (size_t)b * GSTRIDE * 64 * 4;
    const float* zb = z64 + (size_t)b * ZSTRIDE;

    bool rec_main = (l == u_idx);
    bool rec_side = (u_idx == 64) && (l == 63);

    float am = 0.f, as = 1.f;             // g pair, g = am + log2(as)
    float a64m = 0.f, a64s = 1.f;
    float gm = 0.f, gs = 1.f;

    float rA[4], zA[4], rB[4], zB[4], rC[4], zC[4];

#define LOADG(r_, z_, c_) do { int c__ = (c_);                                   \
        *(float4*)(r_) = *(const float4*)(Db + (c__ * 64 + l) * 4);              \
        *(float4*)(z_) = *(const float4*)(zb + 4 * c__);                         \
    } while (0)

#define STEP4(r_, z_, c_) do { int cbase = 4 * (c_);                             \
        _Pragma("unroll")                                                        \
        for (int i = 0; i < 4; ++i) {                                            \
            int s = cbase + i;                                                   \
            scan_step(r_[i], z_[i], am, as, a64m, a64s);                         \
            bool hit = (s == t_sel);                                             \
            gm = (hit && rec_main) ? am   : gm;                                  \
            gs = (hit && rec_main) ? as   : gs;                                  \
            gm = (hit && rec_side) ? a64m : gm;                                  \
            gs = (hit && rec_side) ? a64s : gs;                                  \
        }                                                                        \
        { int e1; as = frexpf(as, &e1); am += (float)e1;                         \
          int e2; a64s = frexpf(a64s, &e2); a64m += (float)e2; }                 \
    } while (0)

    LOADG(rA, zA, 0);
    LOADG(rB, zB, 1);
    LOADG(rC, zC, 2);

    for (int cc = 0; cc < 21; ++cc) {
        STEP4(rA, zA, 3 * cc + 0);  LOADG(rA, zA, 3 * cc + 3);
        STEP4(rB, zB, 3 * cc + 1);  LOADG(rB, zB, 3 * cc + 4);
        STEP4(rC, zC, 3 * cc + 2);  LOADG(rC, zC, 3 * cc + 5);
    }
    STEP4(rA, zA, 63);

    int writer_lane = (u_idx < 64) ? u_idx : 63;
    if (l == writer_lane) {
        float g = (gm + vlog2(gs)) * LN2;
        size_t idx = ((size_t)b * 256 + t_idx) * U1 + u_idx;
        float a  = cum[idx] + g;
        float fb = blank[idx];
        atomicAdd(out, -0.125f * (a + fb));
    }
#undef LOADG
#undef STEP4
}

extern "C" void kernel_launch(void* const* d_in, const int* in_sizes, int n_in,
                              void* d_out, int out_size, void* d_ws, size_t ws_size,
                              hipStream_t stream) {
    const float* logits  = (const float*)d_in[0];
    const int*   targets = (const int*)d_in[1];
    const int*   loglen  = (const int*)d_in[2];
    const int*   tgtlen  = (const int*)d_in[3];

    float* ws    = (float*)d_ws;
    float* blank = ws;                           // B*T*(U+1) = 133120
    float* emit  = blank + BB * TT * U1;         // B*T*U     = 131072
    float* cum   = emit  + BB * TT * UU;         // B*T*(U+1) = 133120
    float* Dg    = cum   + BB * TT * U1;         // 8*66*64*4 = 135168 (padded)
    float* z64   = Dg    + BB * GSTRIDE * 64 * 4; // 8*264    = 2112  (padded)

    const int nrows = BB * TT * U1;
    k_logsm<<<nrows / 4, 256, 0, stream>>>(logits, targets, loglen, tgtlen, blank, emit);
    k_prep<<<(BB * TT) / 4, 256, 0, stream>>>(emit, blank, loglen, cum, Dg, z64, (float*)d_out);
    k_scan<<<BB, 64, 0, stream>>>(Dg, z64, cum, blank, loglen, tgtlen, (float*)d_out);
}

// Round 13
// 81.083 us; speedup vs baseline: 1.1775x; 1.0625x over previous
//
#include <hip/hip_runtime.h>

#define BB 8
#define TT 256
#define UU 64
#define VV 512
#define U1 (UU + 1)
#define NDG 84                  // diagonal groups per batch (84*4=336 slots, d<=323 used)
#define NEG (-1e30f)

#define LOG2E 1.4426950408889634f
#define LN2   0.6931471805599453f
#define NEG_INF (-__builtin_inff())

typedef float floatx4 __attribute__((ext_vector_type(4)));

__device__ __forceinline__ float vexp2(float x) {
    float r; asm("v_exp_f32 %0, %1" : "=v"(r) : "v"(x)); return r;
}
__device__ __forceinline__ float vlog2(float x) {
    float r; asm("v_log_f32 %0, %1" : "=v"(r) : "v"(x)); return r;
}
__device__ __forceinline__ float negabs(float x) {
    return __int_as_float(__float_as_int(x) | 0x80000000u);
}
__device__ __forceinline__ float rdlane63(float x) {
    return __int_as_float(__builtin_amdgcn_readlane(__float_as_int(x), 63));
}

template<int CTRL, int RMASK>
__device__ __forceinline__ float dpp_mov(float v, float oldv) {
    int r = __builtin_amdgcn_update_dpp(__float_as_int(oldv), __float_as_int(v),
                                        CTRL, RMASK, 0xf, false);
    return __int_as_float(r);
}

__device__ __forceinline__ float wave_addscan(float v) {
    v += dpp_mov<0x111, 0xf>(v, 0.f);
    v += dpp_mov<0x112, 0xf>(v, 0.f);
    v += dpp_mov<0x114, 0xf>(v, 0.f);
    v += dpp_mov<0x118, 0xf>(v, 0.f);
    v += dpp_mov<0x142, 0xa>(v, 0.f);
    v += dpp_mov<0x143, 0xc>(v, 0.f);
    return v;
}
__device__ __forceinline__ float wave_maxscan(float v) {
    v = fmaxf(v, dpp_mov<0x111, 0xf>(v, NEG_INF));
    v = fmaxf(v, dpp_mov<0x112, 0xf>(v, NEG_INF));
    v = fmaxf(v, dpp_mov<0x114, 0xf>(v, NEG_INF));
    v = fmaxf(v, dpp_mov<0x118, 0xf>(v, NEG_INF));
    v = fmaxf(v, dpp_mov<0x142, 0xa>(v, NEG_INF));
    v = fmaxf(v, dpp_mov<0x143, 0xc>(v, NEG_INF));
    return v;
}

// Kernel F: fill the diagonal arrays with NEG (dead arms) and zero the output.
__global__ __launch_bounds__(256) void k_fill(float* __restrict__ buf, int n,
                                              float* __restrict__ out) {
    int i = blockIdx.x * 256 + threadIdx.x;
    if (i * 4 < n) {
        floatx4 v = {NEG, NEG, NEG, NEG};
        *(floatx4*)(buf + i * 4) = v;
    }
    if (i == 0) out[0] = 0.f;
}

// Kernel 1: per-row log-softmax; scatter blank/emit lp (log2 domain) into
// diagonal-major arrays. Culled rows leave the NEG fill in place.
__global__ __launch_bounds__(256) void k_logsm(const float* __restrict__ logits,
                                               const int* __restrict__ targets,
                                               const int* __restrict__ loglen,
                                               const int* __restrict__ tgtlen,
                                               float* __restrict__ Bd4,
                                               float* __restrict__ Ed4,
                                               float* __restrict__ B64,
                                               float* __restrict__ E64) {
    int wave = (int)((blockIdx.x * blockDim.x + threadIdx.x) >> 6);
    int lane = threadIdx.x & 63;
    const int nrows = BB * TT * U1;
    if (wave >= nrows) return;
    int u  = wave % U1;
    int bt = wave / U1;
    int b  = bt / TT;
    int t  = bt - b * TT;
    if (t >= loglen[b] || u > tgtlen[b]) return;   // dead row

    const float* row = logits + (size_t)wave * VV;
    floatx4 v0 = __builtin_nontemporal_load((const floatx4*)(row + lane * 4));
    floatx4 v1 = __builtin_nontemporal_load((const floatx4*)(row + 256 + lane * 4));
    float m8 = fmaxf(fmaxf(fmaxf(v0.x, v0.y), fmaxf(v0.z, v0.w)),
                     fmaxf(fmaxf(v1.x, v1.y), fmaxf(v1.z, v1.w)));
    float M = rdlane63(wave_maxscan(m8));
    float s8 = __expf(v0.x - M) + __expf(v0.y - M) + __expf(v0.z - M) + __expf(v0.w - M)
             + __expf(v1.x - M) + __expf(v1.y - M) + __expf(v1.z - M) + __expf(v1.w - M);
    float S = rdlane63(wave_addscan(s8));
    float lse = M + __logf(S);

    if (lane == 0) {
        float blv = (v0.x - lse) * LOG2E;          // blank lp, log2 domain
        if (u < 64) {
            int d = t + u + 1;                     // Bd[d][u] = blank[d-1-u][u]
            Bd4[((b * NDG + (d >> 2)) * 64 + u) * 4 + (d & 3)] = blv;
        } else {
            B64[b * (NDG * 4) + (t + 65)] = blv;   // B64[d] = blank[d-65][64]
        }
    }
    if (u < UU) {
        int tgt = targets[b * UU + u];             // in [1, V)
        int owner = (tgt & 255) >> 2;
        if (lane == owner) {
            int slot = tgt & 3;
            float x0 = (tgt < 256) ? v0.x : v1.x;
            float x1 = (tgt < 256) ? v0.y : v1.y;
            float x2 = (tgt < 256) ? v0.z : v1.z;
            float x3 = (tgt < 256) ? v0.w : v1.w;
            float val = (slot == 0) ? x0 : (slot == 1) ? x1 : (slot == 2) ? x2 : x3;
            float em = (val - lse) * LOG2E;        // emit lp, log2 domain
            if (u < 63) {
                int d = t + u + 1;                 // Ed[d][u+1] = emit[d-(u+1)][u]
                Ed4[((b * NDG + (d >> 2)) * 64 + (u + 1)) * 4 + (d & 3)] = em;
            } else {                               // u == 63 feeds the u=64 side-chain
                E64[b * (NDG * 4) + (t + 64)] = em; // E64[d] = emit[d-64][63]
            }
        }
    }
}

// Kernel 2: anti-diagonal alpha recursion. Lane l owns u=l; one 2-way logadd
// per cell per diagonal. State (m,s): alpha = m + log2(s). u=64 side-chain
// (block-uniform) only when tgtlen[b]==64.
__global__ __launch_bounds__(64) void k_scan(const float* __restrict__ Bd4,
                                             const float* __restrict__ Ed4,
                                             const float* __restrict__ B64,
                                             const float* __restrict__ E64,
                                             const int* __restrict__ loglen,
                                             const int* __restrict__ tgtlen,
                                             float* __restrict__ out) {
    int b = blockIdx.x;
    int l = threadIdx.x;
    int t_idx = loglen[b] - 1;
    int u_idx = tgtlen[b];
    int d_fin = t_idx + u_idx;                    // latch alpha here; +1 latches blank
    const bool need64 = (u_idx == 64);
    const bool rec_main = (l == u_idx);           // false for all lanes if u_idx==64
    const bool rec_side = need64 && (l == 63);

    const float* pB  = Bd4 + (size_t)b * NDG * 256 + l * 4;
    const float* pE  = Ed4 + (size_t)b * NDG * 256 + l * 4;
    const float* p6B = B64 + b * (NDG * 4);
    const float* p6E = E64 + b * (NDG * 4);

    int paddr = (l - 1) << 2;                     // bpermute byte addr (lane0 wraps, killed)
    bool lane0 = (l == 0);

    float Am = lane0 ? 0.f : NEG, As = 1.f;       // alpha[0][0]=0 at d=0
    float A64m = NEG, A64s = 1.f;
    float gm = NEG, gs = 1.f, fb = 0.f;

    floatx4 Xb, Xe, Xb6, Xe6, Yb, Ye, Yb6, Ye6, Zb, Ze, Zb6, Ze6;

#define LOADG(P, g_) do { int gg = (g_);                                         \
        P##b  = *(const floatx4*)(pB  + gg * 256);                               \
        P##e  = *(const floatx4*)(pE  + gg * 256);                               \
        P##b6 = *(const floatx4*)(p6B + gg * 4);                                 \
        P##e6 = *(const floatx4*)(p6E + gg * 4);                                 \
    } while (0)

#define STEP1(bv, ev, b64v, e64v, dd) do { int d_ = (dd);                        \
        float pm = __int_as_float(__builtin_amdgcn_ds_bpermute(paddr,            \
                                   __float_as_int(Am)));                         \
        float ps = __int_as_float(__builtin_amdgcn_ds_bpermute(paddr,            \
                                   __float_as_int(As)));                         \
        pm = lane0 ? NEG : pm;                                                   \
        ps = lane0 ? 1.f : ps;                                                   \
        float ma = Am + (bv), me = pm + (ev);                                    \
        bool c = ma >= me;                                                       \
        float M = fmaxf(ma, me);                                                 \
        float w = vexp2(negabs(ma - me));                                        \
        float bg = c ? As : ps, sm = c ? ps : As;                                \
        float S = fmaf(sm, w, bg);                                               \
        if (need64) {                                                            \
            float sa = A64m + (b64v), se = M + (e64v);                           \
            bool c2 = sa >= se;                                                  \
            float M2 = fmaxf(sa, se);                                            \
            float w2 = vexp2(negabs(sa - se));                                   \
            float bg2 = c2 ? A64s : S, sm2 = c2 ? S : A64s;                      \
            A64s = fmaf(sm2, w2, bg2); A64m = M2;                                \
        }                                                                        \
        Am = M; As = S;                                                          \
        bool hit0 = (d_ == d_fin), hit1 = (d_ == d_fin + 1);                     \
        bool h0m = hit0 && rec_main, h1m = hit1 && rec_main;                     \
        gm = h0m ? M : gm;  gs = h0m ? S : gs;  fb = h1m ? (bv) : fb;            \
        if (need64) {                                                            \
            bool h0s = hit0 && rec_side, h1s = hit1 && rec_side;                 \
            gm = h0s ? A64m : gm; gs = h0s ? A64s : gs;                          \
            fb = h1s ? (b64v) : fb;                                              \
        }                                                                        \
    } while (0)

#define RENORM do {                                                              \
        int e1; As = frexpf(As, &e1); Am += (float)e1;                           \
        if (need64) { int e2; A64s = frexpf(A64s, &e2); A64m += (float)e2; }     \
    } while (0)

#define STEP4(P, g_) do { int gq = (g_);                                         \
        STEP1(P##b.x, P##e.x, P##b6.x, P##e6.x, 4 * gq + 0);                     \
        STEP1(P##b.y, P##e.y, P##b6.y, P##e6.y, 4 * gq + 1);                     \
        STEP1(P##b.z, P##e.z, P##b6.z, P##e6.z, 4 * gq + 2);                     \
        STEP1(P##b.w, P##e.w, P##b6.w, P##e6.w, 4 * gq + 3);                     \
        RENORM;                                                                  \
    } while (0)

    LOADG(X, 0); LOADG(Y, 1); LOADG(Z, 2);

    // group 0: skip d=0 (init cell), run d=1..3
    STEP1(Xb.y, Xe.y, Xb6.y, Xe6.y, 1);
    STEP1(Xb.z, Xe.z, Xb6.z, Xe6.z, 2);
    STEP1(Xb.w, Xe.w, Xb6.w, Xe6.w, 3);
    RENORM;
    LOADG(X, 3);
    STEP4(Y, 1); LOADG(Y, 4);
    STEP4(Z, 2); LOADG(Z, 5);

    for (int cc = 1; cc <= 25; ++cc) {
        STEP4(X, 3 * cc + 0); LOADG(X, 3 * cc + 3);
        STEP4(Y, 3 * cc + 1); LOADG(Y, 3 * cc + 4);
        STEP4(Z, 3 * cc + 2); LOADG(Z, 3 * cc + 5);
    }
    STEP4(X, 78); STEP4(Y, 79); STEP4(Z, 80);     // d up to 323 (>320 slots are inert NEG)

    int wl = need64 ? 63 : u_idx;
    if (l == wl) {
        float g = gm + vlog2(gs);
        atomicAdd(out, -0.125f * (g + fb) * LN2);
    }
#undef LOADG
#undef STEP1
#undef RENORM
#undef STEP4
}

extern "C" void kernel_launch(void* const* d_in, const int* in_sizes, int n_in,
                              void* d_out, int out_size, void* d_ws, size_t ws_size,
                              hipStream_t stream) {
    const float* logits  = (const float*)d_in[0];
    const int*   targets = (const int*)d_in[1];
    const int*   loglen  = (const int*)d_in[2];
    const int*   tgtlen  = (const int*)d_in[3];

    float* ws  = (float*)d_ws;
    float* Bd4 = ws;                               // 8*84*64*4 = 172032
    float* Ed4 = Bd4 + BB * NDG * 256;             // 172032
    float* B64 = Ed4 + BB * NDG * 256;             // 8*336 = 2688
    float* E64 = B64 + BB * (NDG * 4);             // 2688
    const int nfill = BB * NDG * 256 * 2 + BB * (NDG * 4) * 2;   // 349440

    k_fill<<<(nfill / 4 + 255) / 256, 256, 0, stream>>>(Bd4, nfill, (float*)d_out);
    const int nrows = BB * TT * U1;
    k_logsm<<<nrows / 4, 256, 0, stream>>>(logits, targets, loglen, tgtlen,
                                           Bd4, Ed4, B64, E64);
    k_scan<<<BB, 64, 0, stream>>>(Bd4, Ed4, B64, E64, loglen, tgtlen, (float*)d_out);
}